// Round 1
// baseline (717.285 us; speedup 1.0000x reference)
//
#include <hip/hip_runtime.h>

// LIF neuron: v_t = ALPHA*v_{t-1} + (x_t . w) - V_TH*z_{t-1}; z_t = 1[v_t > V_TH]
// x: [B=128, T=1000, N=1024] fp32, w: [N] fp32.
// Out: v_seq [B,T] ++ z_seq [B,T], flat fp32.
//
// NOTE (R2 post-mortem): dur_us includes the harness's per-iteration restore
// (~490-520 us: 2 GB ws poison @ ~325 us + 524 MB d_in restore). Kernel floor
// is x-read 524 MB / 6.3 TB/s ~= 83 us.
//
// R3: single fused launch. Blocks 1..8000 are dot producers with a TILE-MAJOR
// row mapping (tile = 8 timesteps x 128 batches = 1024 rows); block 0 is the
// sequential scan consumer, polling one relaxed agent-scope counter per tile.
// The scan now overlaps the dot instead of serializing after it (removes the
// full-grid drain + 2nd launch + ~15-30 us scan tail). Per-row dot math is
// bit-identical to R2 (fp64 chains, same butterfly), so drive/v/z values are
// unchanged.
//
// Visibility without wbl2/inv storms: drive stores + counter adds + consumer
// drive loads are all RELAXED AGENT-scope atomics -> performed at the
// device-coherent point (L3) on gfx950. Ordering producer-side comes from the
// compiler's vmcnt(0) drain at __syncthreads() before the single per-block
// counter add (64 blocks x 16 rows per tile).

#define ALPHA 0.995f
#define V_TH 2.0f

constexpr int B = 128;
constexpr int T = 1000;
constexpr int N = 1024;
constexpr int TILE_T = 8;                  // timesteps per signal tile
constexpr int NTILES = T / TILE_T;         // 125 (exact)
constexpr int ROWS_PER_TILE = TILE_T * B;  // 1024

typedef float f32x4 __attribute__((ext_vector_type(4)));

__global__ __launch_bounds__(256) void lif_fused_kernel(
    const float* __restrict__ x, const float* __restrict__ w,
    float* __restrict__ out, float* __restrict__ drive_t,
    unsigned int* __restrict__ tile_cnt) {
    // v/z store-staging only (drive is read straight from L3 by the consumer).
    // [B][9]: stride 9 floats -> worst 2-way LDS aliasing (free on CDNA4).
    __shared__ float s_v[B][TILE_T + 1];
    __shared__ float s_z[B][TILE_T + 1];
    const int tid = threadIdx.x;

    if (blockIdx.x == 0) {
        // ------------------- consumer: sequential LIF scan -------------------
        float v = 0.0f, z = 0.0f;
        for (int g = 0; g < NTILES; ++g) {
            if (tid == 0) {
                while (__hip_atomic_load(&tile_cnt[g], __ATOMIC_RELAXED,
                                         __HIP_MEMORY_SCOPE_AGENT) <
                       (unsigned)ROWS_PER_TILE)
                    __builtin_amdgcn_s_sleep(8);
            }
            __syncthreads();  // tile g fully at coherent point

            const int t0 = g * TILE_T;
            if (tid < B) {
                // batch the 8 L3 loads (independent of the recurrence)
                float d[TILE_T];
#pragma unroll
                for (int j = 0; j < TILE_T; ++j)
                    d[j] = __hip_atomic_load(&drive_t[(t0 + j) * B + tid],
                                             __ATOMIC_RELAXED,
                                             __HIP_MEMORY_SCOPE_AGENT);
                float vv = v, zz = z;
#pragma unroll
                for (int j = 0; j < TILE_T; ++j) {
                    vv = ALPHA * vv + d[j] - V_TH * zz;
                    zz = (vv - V_TH > 0.0f) ? 1.0f : 0.0f;
                    s_v[tid][j] = vv;
                    s_z[tid][j] = zz;
                }
                v = vv; z = zz;
            }
            __syncthreads();

            // 512 aligned f32x4 stores (v + z), 2 per thread
            {
                const int bb = tid >> 1;
                const int j4 = (tid & 1) * 4;
                f32x4 vq = { s_v[bb][j4], s_v[bb][j4 + 1],
                             s_v[bb][j4 + 2], s_v[bb][j4 + 3] };
                *(f32x4*)(out + (long long)bb * T + t0 + j4) = vq;
                f32x4 zq = { s_z[bb][j4], s_z[bb][j4 + 1],
                             s_z[bb][j4 + 2], s_z[bb][j4 + 3] };
                *(f32x4*)(out + (long long)(B + bb) * T + t0 + j4) = zq;
            }
            __syncthreads();  // s_v/s_z reuse next tile
        }
        return;
    }

    // ---------------------- producer: dot(x_row, w) --------------------------
    // Tile-major row index r = g*1024 + b*8 + j  (g=tile, b=batch, j=t offset).
    // One wave owns 4 consecutive r (same g, same b, t..t+3) -> its 4 x-rows
    // are 16 KB CONTIGUOUS, same streaming pattern as R2.
    const int lane = tid & 63;
    const int gwave = (blockIdx.x - 1) * 4 + (tid >> 6);  // 0..31999
    const int base = gwave * 4;                           // 0..127996
    const int g  = base >> 10;        // tile (block-uniform: 16 rows/block)
    const int rem = base & 1023;
    const int b  = rem >> 3;          // batch row
    const int j0 = rem & 7;           // 0 or 4
    const int t0 = g * TILE_T + j0;

    const float* wp = w + lane * 4;
    const f32x4 w0 = *(const f32x4*)(wp);
    const f32x4 w1 = *(const f32x4*)(wp + 256);
    const f32x4 w2 = *(const f32x4*)(wp + 512);
    const f32x4 w3 = *(const f32x4*)(wp + 768);

    const float* xb = x + ((long long)b * T + t0) * N + lane * 4;

#pragma unroll
    for (int i = 0; i < 4; i += 2) {
        const f32x4* xr0 = (const f32x4*)(xb + (long long)i * N);
        const f32x4* xr1 = (const f32x4*)((const float*)xr0 + N);
        // issue all 8 loads (8 KB/wave) before any use; nontemporal: x is
        // streamed once, keep it from thrashing L2
        const f32x4 a0 = __builtin_nontemporal_load(xr0);
        const f32x4 a1 = __builtin_nontemporal_load(xr0 + 64);
        const f32x4 a2 = __builtin_nontemporal_load(xr0 + 128);
        const f32x4 a3 = __builtin_nontemporal_load(xr0 + 192);
        const f32x4 b0 = __builtin_nontemporal_load(xr1);
        const f32x4 b1 = __builtin_nontemporal_load(xr1 + 64);
        const f32x4 b2 = __builtin_nontemporal_load(xr1 + 128);
        const f32x4 b3 = __builtin_nontemporal_load(xr1 + 192);

        // 8 independent 4-deep fp64 chains (bit-identical to R2)
        double s0 = (double)a0.x*w0.x + (double)a0.y*w0.y + (double)a0.z*w0.z + (double)a0.w*w0.w;
        double s1 = (double)a1.x*w1.x + (double)a1.y*w1.y + (double)a1.z*w1.z + (double)a1.w*w1.w;
        double s2 = (double)a2.x*w2.x + (double)a2.y*w2.y + (double)a2.z*w2.z + (double)a2.w*w2.w;
        double s3 = (double)a3.x*w3.x + (double)a3.y*w3.y + (double)a3.z*w3.z + (double)a3.w*w3.w;
        double t0_ = (double)b0.x*w0.x + (double)b0.y*w0.y + (double)b0.z*w0.z + (double)b0.w*w0.w;
        double t1_ = (double)b1.x*w1.x + (double)b1.y*w1.y + (double)b1.z*w1.z + (double)b1.w*w1.w;
        double t2_ = (double)b2.x*w2.x + (double)b2.y*w2.y + (double)b2.z*w2.z + (double)b2.w*w2.w;
        double t3_ = (double)b3.x*w3.x + (double)b3.y*w3.y + (double)b3.z*w3.z + (double)b3.w*w3.w;
        double accA = (s0 + s1) + (s2 + s3);
        double accB = (t0_ + t1_) + (t2_ + t3_);

        // two interleaved butterfly reductions (latencies overlap)
#pragma unroll
        for (int off = 32; off >= 1; off >>= 1) {
            accA += __shfl_down(accA, off);
            accB += __shfl_down(accB, off);
        }

        if (lane == 0) {
            // agent-scope (coherent-point) stores: visible cross-XCD without
            // a release fence
            __hip_atomic_store(&drive_t[(t0 + i) * B + b], (float)accA,
                               __ATOMIC_RELAXED, __HIP_MEMORY_SCOPE_AGENT);
            __hip_atomic_store(&drive_t[(t0 + i + 1) * B + b], (float)accB,
                               __ATOMIC_RELAXED, __HIP_MEMORY_SCOPE_AGENT);
        }
    }

    // All 4 waves of this block feed the SAME tile g (16 rows/block, tiles are
    // 1024-row aligned). __syncthreads() drains each wave's vmcnt -> all 16
    // drive values are at the coherent point before the single counter add.
    __syncthreads();
    if (tid == 0)
        __hip_atomic_fetch_add(&tile_cnt[g], 16u, __ATOMIC_RELAXED,
                               __HIP_MEMORY_SCOPE_AGENT);
}

extern "C" void kernel_launch(void* const* d_in, const int* in_sizes, int n_in,
                              void* d_out, int out_size, void* d_ws, size_t ws_size,
                              hipStream_t stream) {
    const float* x = (const float*)d_in[0];   // [B,T,N]
    const float* w = (const float*)d_in[1];   // [N]
    float* out = (float*)d_out;               // v[B,T] ++ z[B,T]
    float* drive_t = (float*)d_ws;            // [T,B] scratch, 500 KB
    unsigned int* tile_cnt =
        (unsigned int*)((char*)d_ws + 512 * 1024);  // 125 counters

    // counters are poisoned each iteration -> zero them (graph-capturable)
    hipMemsetAsync(tile_cnt, 0, NTILES * sizeof(unsigned int), stream);

    // block 0 = scan consumer; blocks 1..8000 = dot producers (4 waves x 4 rows)
    lif_fused_kernel<<<8001, 256, 0, stream>>>(x, w, out, drive_t, tile_cnt);
}

// Round 2
// 690.903 us; speedup vs baseline: 1.0382x; 1.0382x over previous
//
#include <hip/hip_runtime.h>

// LIF neuron: v_t = ALPHA*v_{t-1} + (x_t . w) - V_TH*z_{t-1}; z_t = 1[v_t > V_TH]
// x: [B=128, T=1000, N=1024] fp32, w: [N] fp32.
// Out: v_seq [B,T] ++ z_seq [B,T], flat fp32.
//
// NOTE: dur_us includes the harness's per-iteration restore (~490-520 us:
// 2 GB ws poison @ ~325 us + 524 MB d_in restore). Kernel floor is x-read
// 524 MB / 6.3 TB/s ~= 83 us.
//
// R4 (post-mortem of R3's +31 us regression): fusion kept, consumer fixed.
// R3's consumer (125 tiles x {poll@512cyc + 3 syncthreads + L3 loads + LDS})
// had ~150-250 us of serial chain -- MORE than the producers' ~110 us, so it
// lagged and extended the kernel instead of hiding under it. R4:
//   - TILE_T=40 -> 25 tiles (5x fewer fixed-latency rounds)
//   - consumer: no LDS, no barriers; waves 2-3 exit; 128 lanes spin-poll,
//     40 upfront L3 loads, recurrence, direct per-thread f32x4 stores.
//     Chain ~= 25 x ~1100 cyc ~= 12 us total -> always ahead of producers.
//   - producers: ZERO LDS; b-major-within-tile mapping keeps 16 KB/wave and
//     160 KB/batch-slice contiguity (R3's 32 KB chunks -> 160 KB).
//   - dot math + store/counter protocol bit-identical to R3 (proven correct).

#define ALPHA 0.995f
#define V_TH 2.0f

constexpr int B = 128;
constexpr int T = 1000;
constexpr int N = 1024;
constexpr int TILE_T = 40;                     // timesteps per signal tile
constexpr int NTILES = T / TILE_T;             // 25 (exact)
constexpr int ROWS_PER_TILE = TILE_T * B;      // 5120
constexpr int BLOCKS_PER_TILE = ROWS_PER_TILE / 16;  // 320

typedef float f32x4 __attribute__((ext_vector_type(4)));

__global__ __launch_bounds__(256) void lif_fused_kernel(
    const float* __restrict__ x, const float* __restrict__ w,
    float* __restrict__ out, float* __restrict__ drive_t,
    unsigned int* __restrict__ tile_cnt) {
    const int tid = threadIdx.x;

    if (blockIdx.x == 0) {
        // ---------------- consumer: sequential LIF scan ----------------
        // One thread per batch row; waves 2,3 contribute nothing -> exit.
        if (tid >= B) return;
        float v = 0.0f, z = 0.0f;
        for (int g = 0; g < NTILES; ++g) {
            // all 128 lanes spin on the same counter dword (coalesced
            // broadcast); no barrier needed -> per-wave uniform exit
            while (__hip_atomic_load(&tile_cnt[g], __ATOMIC_RELAXED,
                                     __HIP_MEMORY_SCOPE_AGENT) <
                   (unsigned)ROWS_PER_TILE)
                __builtin_amdgcn_s_sleep(2);

            const int t0 = g * TILE_T;
            // batch all 40 coherent-point loads (independent of recurrence);
            // latency exposed once per tile, hidden after first
            float d[TILE_T];
#pragma unroll
            for (int j = 0; j < TILE_T; ++j)
                d[j] = __hip_atomic_load(&drive_t[(t0 + j) * B + tid],
                                         __ATOMIC_RELAXED,
                                         __HIP_MEMORY_SCOPE_AGENT);

            // recurrence + direct aligned f32x4 stores (tid*1000 and t0 are
            // multiples of 4 -> 16B-aligned; 1 MB total out, amplification
            // from stride-4000B pattern costs ~1-2 us, fire-and-forget)
            float* vout = out + (long long)tid * T + t0;
            float* zout = out + (long long)(B + tid) * T + t0;
#pragma unroll
            for (int j4 = 0; j4 < TILE_T; j4 += 4) {
                f32x4 vq, zq;
#pragma unroll
                for (int k = 0; k < 4; ++k) {
                    v = ALPHA * v + d[j4 + k] - V_TH * z;
                    z = (v - V_TH > 0.0f) ? 1.0f : 0.0f;
                    vq[k] = v;
                    zq[k] = z;
                }
                *(f32x4*)(vout + j4) = vq;
                *(f32x4*)(zout + j4) = zq;
            }
        }
        return;
    }

    // ---------------------- producer: dot(x_row, w) ----------------------
    // Tile-major, b-major-within-tile row order:
    //   R = (blockIdx-1)*16 + wave*4;  g = R/5120;  rin = R%5120;
    //   b = rin/40;  j0 = rin%40;  t = g*40 + j0 .. +3  (same b: 4|rin, 4|40)
    // -> each wave's 4 x-rows are 16 KB CONTIGUOUS (same as R2); each
    // (b, tile) slice is 160 KB contiguous, read by 2.5 consecutive blocks.
    const int lane = tid & 63;
    const int R = (blockIdx.x - 1) * 16 + ((tid >> 6) << 2);
    const int g = R / ROWS_PER_TILE;          // block-uniform (16 | 5120)
    const int rin = R - g * ROWS_PER_TILE;
    const int b = rin / TILE_T;
    const int j0 = rin - b * TILE_T;
    const int t0 = g * TILE_T + j0;

    const float* wp = w + lane * 4;
    const f32x4 w0 = *(const f32x4*)(wp);
    const f32x4 w1 = *(const f32x4*)(wp + 256);
    const f32x4 w2 = *(const f32x4*)(wp + 512);
    const f32x4 w3 = *(const f32x4*)(wp + 768);

    const float* xb = x + ((long long)b * T + t0) * N + lane * 4;

#pragma unroll
    for (int i = 0; i < 4; i += 2) {
        const f32x4* xr0 = (const f32x4*)(xb + (long long)i * N);
        const f32x4* xr1 = (const f32x4*)((const float*)xr0 + N);
        // issue all 8 loads (8 KB/wave) before any use; nontemporal: x is
        // streamed once, keep it from thrashing L2
        const f32x4 a0 = __builtin_nontemporal_load(xr0);
        const f32x4 a1 = __builtin_nontemporal_load(xr0 + 64);
        const f32x4 a2 = __builtin_nontemporal_load(xr0 + 128);
        const f32x4 a3 = __builtin_nontemporal_load(xr0 + 192);
        const f32x4 b0 = __builtin_nontemporal_load(xr1);
        const f32x4 b1 = __builtin_nontemporal_load(xr1 + 64);
        const f32x4 b2 = __builtin_nontemporal_load(xr1 + 128);
        const f32x4 b3 = __builtin_nontemporal_load(xr1 + 192);

        // 8 independent 4-deep fp64 chains (bit-identical to R2/R3)
        double s0 = (double)a0.x*w0.x + (double)a0.y*w0.y + (double)a0.z*w0.z + (double)a0.w*w0.w;
        double s1 = (double)a1.x*w1.x + (double)a1.y*w1.y + (double)a1.z*w1.z + (double)a1.w*w1.w;
        double s2 = (double)a2.x*w2.x + (double)a2.y*w2.y + (double)a2.z*w2.z + (double)a2.w*w2.w;
        double s3 = (double)a3.x*w3.x + (double)a3.y*w3.y + (double)a3.z*w3.z + (double)a3.w*w3.w;
        double t0_ = (double)b0.x*w0.x + (double)b0.y*w0.y + (double)b0.z*w0.z + (double)b0.w*w0.w;
        double t1_ = (double)b1.x*w1.x + (double)b1.y*w1.y + (double)b1.z*w1.z + (double)b1.w*w1.w;
        double t2_ = (double)b2.x*w2.x + (double)b2.y*w2.y + (double)b2.z*w2.z + (double)b2.w*w2.w;
        double t3_ = (double)b3.x*w3.x + (double)b3.y*w3.y + (double)b3.z*w3.z + (double)b3.w*w3.w;
        double accA = (s0 + s1) + (s2 + s3);
        double accB = (t0_ + t1_) + (t2_ + t3_);

        // two interleaved butterfly reductions (latencies overlap)
#pragma unroll
        for (int off = 32; off >= 1; off >>= 1) {
            accA += __shfl_down(accA, off);
            accB += __shfl_down(accB, off);
        }

        if (lane == 0) {
            // agent-scope (coherent-point) stores: visible cross-XCD without
            // a release fence
            __hip_atomic_store(&drive_t[(t0 + i) * B + b], (float)accA,
                               __ATOMIC_RELAXED, __HIP_MEMORY_SCOPE_AGENT);
            __hip_atomic_store(&drive_t[(t0 + i + 1) * B + b], (float)accB,
                               __ATOMIC_RELAXED, __HIP_MEMORY_SCOPE_AGENT);
        }
    }

    // All 4 waves of this block feed the SAME tile g (5120 % 16 == 0).
    // __syncthreads() drains each wave's vmcnt -> all 16 drive values are at
    // the coherent point before the single counter add.
    __syncthreads();
    if (tid == 0)
        __hip_atomic_fetch_add(&tile_cnt[g], 16u, __ATOMIC_RELAXED,
                               __HIP_MEMORY_SCOPE_AGENT);
}

extern "C" void kernel_launch(void* const* d_in, const int* in_sizes, int n_in,
                              void* d_out, int out_size, void* d_ws, size_t ws_size,
                              hipStream_t stream) {
    const float* x = (const float*)d_in[0];   // [B,T,N]
    const float* w = (const float*)d_in[1];   // [N]
    float* out = (float*)d_out;               // v[B,T] ++ z[B,T]
    float* drive_t = (float*)d_ws;            // [T,B] scratch, 500 KB
    unsigned int* tile_cnt =
        (unsigned int*)((char*)d_ws + 512 * 1024);  // 25 counters

    // counters are poisoned each iteration -> zero them (graph-capturable)
    hipMemsetAsync(tile_cnt, 0, NTILES * sizeof(unsigned int), stream);

    // block 0 = scan consumer; blocks 1..8000 = dot producers (4 waves x 4 rows)
    lif_fused_kernel<<<8001, 256, 0, stream>>>(x, w, out, drive_t, tile_cnt);
}

// Round 3
// 669.091 us; speedup vs baseline: 1.0720x; 1.0326x over previous
//
#include <hip/hip_runtime.h>

// LIF neuron: v_t = ALPHA*v_{t-1} + (x_t . w) - V_TH*z_{t-1}; z_t = 1[v_t > V_TH]
// x: [B=128, T=1000, N=1024] fp32, w: [N] fp32.
// Out: v_seq [B,T] ++ z_seq [B,T], flat fp32.
//
// NOTE: dur_us includes the harness's per-iteration restore (~490-600 us:
// 2 GB ws poison @ ~325 us + d_in restore). Kernel floor is x-read
// 524 MB / 6.3 TB/s ~= 83 us.
//
// R5 (post-mortem of R3/R4 fusion arc): fused producer-consumer netted ~0
// vs the two-kernel structure (R2 686.5 / R3 717.3 / R4 690.9) -- the
// overlap win (~20 us) was cancelled by producer perturbation (tile-major
// mapping shrank per-block contiguity 64 KB -> 16 KB, atomic stores, counter
// epilogue). TLP arithmetic says the dot is BW-bound (avg outstanding
// bytes/CU ~60 KB >> 9 KB needed for 6.3 TB/s), so producer streaming
// pattern is what matters. R5 = R2's proven dot kernel REVERTED BIT-FOR-BIT
// + the leaner consumer validated in R4 (no LDS, no barriers, direct f32x4
// stores) as a standalone second kernel.

#define ALPHA 0.995f
#define V_TH 2.0f

constexpr int B = 128;
constexpr int T = 1000;
constexpr int N = 1024;
constexpr int TILE_T = 40;             // scan tile (25 tiles exactly)

typedef float f32x4 __attribute__((ext_vector_type(4)));

// ---------------------------------------------------------------------------
// Kernel 1 (identical to R2 best): drive_t[t*B + b] = dot(x[row,:], w),
// row = b*T + t. 8000 blocks x 4 waves; each wave owns 4 rows, processed as
// a 2-row software pipeline (8 KB of loads in flight, 8 independent 4-deep
// fp64 chains, two interleaved shuffle-reduce chains). 32000 waves queued
// deep (~31/SIMD) so the per-row reduce latency hides.
// ---------------------------------------------------------------------------
__global__ __launch_bounds__(256) void lif_dot_kernel(
    const float* __restrict__ x, const float* __restrict__ w,
    float* __restrict__ drive_t) {
    const int lane = threadIdx.x & 63;
    const int gwave = blockIdx.x * 4 + (threadIdx.x >> 6);  // 0..31999
    const int base_row = gwave * 4;                         // 4 rows/wave

    const float* wp = w + lane * 4;
    const f32x4 w0 = *(const f32x4*)(wp);
    const f32x4 w1 = *(const f32x4*)(wp + 256);
    const f32x4 w2 = *(const f32x4*)(wp + 512);
    const f32x4 w3 = *(const f32x4*)(wp + 768);

#pragma unroll
    for (int i = 0; i < 4; i += 2) {
        const f32x4* xr0 = (const f32x4*)(x + (long long)(base_row + i) * N + lane * 4);
        const f32x4* xr1 = (const f32x4*)((const float*)xr0 + N);
        // issue all 8 loads (8 KB/wave) before any use; nontemporal: x is
        // streamed once, keep it from thrashing L2
        const f32x4 a0 = __builtin_nontemporal_load(xr0);
        const f32x4 a1 = __builtin_nontemporal_load(xr0 + 64);
        const f32x4 a2 = __builtin_nontemporal_load(xr0 + 128);
        const f32x4 a3 = __builtin_nontemporal_load(xr0 + 192);
        const f32x4 b0 = __builtin_nontemporal_load(xr1);
        const f32x4 b1 = __builtin_nontemporal_load(xr1 + 64);
        const f32x4 b2 = __builtin_nontemporal_load(xr1 + 128);
        const f32x4 b3 = __builtin_nontemporal_load(xr1 + 192);

        // 8 independent 4-deep fp64 chains
        double s0 = (double)a0.x*w0.x + (double)a0.y*w0.y + (double)a0.z*w0.z + (double)a0.w*w0.w;
        double s1 = (double)a1.x*w1.x + (double)a1.y*w1.y + (double)a1.z*w1.z + (double)a1.w*w1.w;
        double s2 = (double)a2.x*w2.x + (double)a2.y*w2.y + (double)a2.z*w2.z + (double)a2.w*w2.w;
        double s3 = (double)a3.x*w3.x + (double)a3.y*w3.y + (double)a3.z*w3.z + (double)a3.w*w3.w;
        double t0 = (double)b0.x*w0.x + (double)b0.y*w0.y + (double)b0.z*w0.z + (double)b0.w*w0.w;
        double t1 = (double)b1.x*w1.x + (double)b1.y*w1.y + (double)b1.z*w1.z + (double)b1.w*w1.w;
        double t2 = (double)b2.x*w2.x + (double)b2.y*w2.y + (double)b2.z*w2.z + (double)b2.w*w2.w;
        double t3 = (double)b3.x*w3.x + (double)b3.y*w3.y + (double)b3.z*w3.z + (double)b3.w*w3.w;
        double accA = (s0 + s1) + (s2 + s3);
        double accB = (t0 + t1) + (t2 + t3);

        // two interleaved butterfly reductions (latencies overlap)
#pragma unroll
        for (int off = 32; off >= 1; off >>= 1) {
            accA += __shfl_down(accA, off);
            accB += __shfl_down(accB, off);
        }

        if (lane == 0) {
            const int row = base_row + i;
            const int b1_ = row / T;
            const int t1_ = row - b1_ * T;
            drive_t[t1_ * B + b1_] = (float)accA;
            const int row2 = row + 1;
            const int b2_ = row2 / T;
            const int t2_ = row2 - b2_ * T;
            drive_t[t2_ * B + b2_] = (float)accB;
        }
    }
}

// ---------------------------------------------------------------------------
// Kernel 2: sequential LIF scan — R4's validated lean consumer, standalone.
// 1 block x 128 threads, one thread per batch row. No LDS, no barriers.
// Per 40-step tile: 40 upfront coalesced loads (drive is [T][B] -> each j is
// a contiguous 512 B line across the 128 threads, L2/L3-resident), then the
// serial recurrence with direct aligned f32x4 stores (b*1000 and t0 are
// multiples of 4). ~25 tiles x ~1k cyc ~= 10 us.
// ---------------------------------------------------------------------------
__global__ __launch_bounds__(128) void lif_scan_kernel(
    const float* __restrict__ drive_t, float* __restrict__ out) {
    const int b = threadIdx.x;  // 0..127
    float v = 0.0f, z = 0.0f;
    for (int t0 = 0; t0 < T; t0 += TILE_T) {
        // batch all 40 loads (independent of the recurrence)
        float d[TILE_T];
#pragma unroll
        for (int j = 0; j < TILE_T; ++j)
            d[j] = drive_t[(t0 + j) * B + b];

        float* vout = out + (long long)b * T + t0;
        float* zout = out + (long long)(B + b) * T + t0;
#pragma unroll
        for (int j4 = 0; j4 < TILE_T; j4 += 4) {
            f32x4 vq, zq;
#pragma unroll
            for (int k = 0; k < 4; ++k) {
                v = ALPHA * v + d[j4 + k] - V_TH * z;
                z = (v - V_TH > 0.0f) ? 1.0f : 0.0f;
                vq[k] = v;
                zq[k] = z;
            }
            *(f32x4*)(vout + j4) = vq;
            *(f32x4*)(zout + j4) = zq;
        }
    }
}

extern "C" void kernel_launch(void* const* d_in, const int* in_sizes, int n_in,
                              void* d_out, int out_size, void* d_ws, size_t ws_size,
                              hipStream_t stream) {
    const float* x = (const float*)d_in[0];   // [B,T,N]
    const float* w = (const float*)d_in[1];   // [N]
    float* out = (float*)d_out;               // v[B,T] ++ z[B,T]
    float* drive_t = (float*)d_ws;            // [T,B] scratch, 512 KB

    // 32000 waves x 4 rows = 128000 rows
    lif_dot_kernel<<<8000, 256, 0, stream>>>(x, w, drive_t);
    lif_scan_kernel<<<1, 128, 0, stream>>>(drive_t, out);
}